// Round 3
// baseline (490.506 us; speedup 1.0000x reference)
//
#include <hip/hip_runtime.h>
#include <math.h>

#define N_NODES 100000
#define N_EDGES 1600000
#define IN_DIM 512
#define OUT_DIM 64
#define NB 1024                    // sort buckets (dst>>7)
#define NPB 128                    // partition blocks
#define CHUNK (N_EDGES / NPB)      // 12500 edges per partition block (exact)
#define N_BUCKETS_USED 782         // ceil(100000/128)
#define N_TILES (N_NODES / 16)     // 6250 exact
#define GEMM_WAVES 4096            // 512 blocks x 8 waves

typedef __attribute__((ext_vector_type(8))) short short8;
typedef __attribute__((ext_vector_type(4))) float float4v;

__device__ __forceinline__ unsigned short f2bf(float f) {   // RNE fp32->bf16
    unsigned int u = __float_as_uint(f);
    u += 0x7fffu + ((u >> 16) & 1u);
    return (unsigned short)(u >> 16);
}
__device__ __forceinline__ float bf2f(unsigned short s) {
    return __uint_as_float(((unsigned int)s) << 16);
}
__device__ __forceinline__ short8 cvt8(float4v lo, float4v hi) {
    union { short8 s8; unsigned short us[8]; } af;
    af.us[0] = f2bf(lo.x); af.us[1] = f2bf(lo.y);
    af.us[2] = f2bf(lo.z); af.us[3] = f2bf(lo.w);
    af.us[4] = f2bf(hi.x); af.us[5] = f2bf(hi.y);
    af.us[6] = f2bf(hi.z); af.us[7] = f2bf(hi.w);
    return af.s8;
}

// ---------------- pass 1: per-block bucket histogram ----------------
__global__ __launch_bounds__(256) void k_hist1(const int* __restrict__ dst,
                                               int* __restrict__ blockHist) {
    __shared__ int hist[NB];
    const int t = threadIdx.x, b = blockIdx.x;
    for (int k = t; k < NB; k += 256) hist[k] = 0;
    __syncthreads();
    const int e0 = b * CHUNK;
    for (int i = t; i < CHUNK; i += 256)
        atomicAdd(&hist[dst[e0 + i] >> 7], 1);
    __syncthreads();
    for (int k = t; k < NB; k += 256) blockHist[b * NB + k] = hist[k];
}

// ---------------- pass 2: bucket bases + per-(block,bucket) starts ----------------
__global__ __launch_bounds__(256) void k_offsets(const int* __restrict__ blockHist,
                                                 int* __restrict__ blockStart,
                                                 int* __restrict__ bucketBase) {
    __shared__ int colsum[NB];
    __shared__ int bbase[NB + 1];
    __shared__ int wtot[4];
    const int t = threadIdx.x, lane = t & 63, w = t >> 6;
    for (int k = t; k < NB; k += 256) {
        int s = 0;
        for (int b = 0; b < NPB; ++b) s += blockHist[b * NB + k];
        colsum[k] = s;
    }
    __syncthreads();
    int c0 = colsum[t * 4 + 0], c1 = colsum[t * 4 + 1];
    int c2 = colsum[t * 4 + 2], c3 = colsum[t * 4 + 3];
    int tsum = c0 + c1 + c2 + c3;
    int incl = tsum;
#pragma unroll
    for (int off = 1; off < 64; off <<= 1) {
        int u = __shfl_up(incl, off, 64);
        if (lane >= off) incl += u;
    }
    if (lane == 63) wtot[w] = incl;
    __syncthreads();
    int woff = 0;
#pragma unroll
    for (int k2 = 0; k2 < 4; ++k2) if (k2 < w) woff += wtot[k2];
    int excl = woff + incl - tsum;
    bbase[t * 4 + 0] = excl;
    bbase[t * 4 + 1] = excl + c0;
    bbase[t * 4 + 2] = excl + c0 + c1;
    bbase[t * 4 + 3] = excl + c0 + c1 + c2;
    if (t == 255) bbase[NB] = excl + tsum;   // == N_EDGES
    __syncthreads();
    for (int k = t; k < NB + 1; k += 256) bucketBase[k] = bbase[k];
    for (int k = t; k < NB; k += 256) {
        int run = bbase[k];
        for (int b = 0; b < NPB; ++b) {
            blockStart[b * NB + k] = run;
            run += blockHist[b * NB + k];
        }
    }
}

// ---------------- pass 3: partition edges into buckets (packed codes) ----------------
__global__ __launch_bounds__(256) void k_partition(const int* __restrict__ dst,
                                                   const int* __restrict__ src,
                                                   const int* __restrict__ blockStart,
                                                   int* __restrict__ parts) {
    __shared__ int cursor[NB];
    const int t = threadIdx.x, b = blockIdx.x;
    for (int k = t; k < NB; k += 256) cursor[k] = blockStart[b * NB + k];
    __syncthreads();
    const int e0 = b * CHUNK;
    for (int i = t; i < CHUNK; i += 256) {
        int d = dst[e0 + i];
        int s = src[e0 + i];
        int k = d >> 7;
        int pos = atomicAdd(&cursor[k], 1);          // LDS atomic (fast)
        parts[pos] = ((d & 127) << 17) | s;           // src < 2^17
    }
}

// ---------------- pass 4: per-bucket counting sort -> deg, row_ptr, csr ----------------
__global__ __launch_bounds__(256) void k_bucket(const int* __restrict__ parts,
                                                const int* __restrict__ bucketBase,
                                                int* __restrict__ degi,
                                                int* __restrict__ row_ptr,
                                                int* __restrict__ csr) {
    __shared__ int cnt[128];
    __shared__ int cur[128];
    __shared__ int wtot[2];
    const int t = threadIdx.x, k = blockIdx.x;
    const int base = bucketBase[k];
    const int n    = bucketBase[k + 1] - base;
    if (t < 128) cnt[t] = 0;
    __syncthreads();
    for (int i = t; i < n; i += 256)
        atomicAdd(&cnt[parts[base + i] >> 17], 1);
    __syncthreads();
    int incl = 0, v = 0;
    if (t < 128) {
        int lane = t & 63;
        v = cnt[t];
        incl = v;
#pragma unroll
        for (int off = 1; off < 64; off <<= 1) {
            int u = __shfl_up(incl, off, 64);
            if (lane >= off) incl += u;
        }
        if (lane == 63) wtot[t >> 6] = incl;
    }
    __syncthreads();
    if (t < 128) {
        int excl = incl - v + ((t >> 6) ? wtot[0] : 0);
        cur[t] = excl;
        int node = k * 128 + t;
        if (node < N_NODES) {
            degi[node]    = v;
            row_ptr[node] = base + excl;
        }
    }
    __syncthreads();
    for (int i = t; i < n; i += 256) {
        int code = parts[base + i];
        int nl = code >> 17, s = code & 0x1FFFF;
        int pos = atomicAdd(&cur[nl], 1);            // LDS atomic
        csr[base + pos] = s;                         // contiguous ~8KB region, L2-resident
    }
}

// ---------------- W swizzle: fp32 [512][64] -> bf16 B-fragment order ----------------
__global__ __launch_bounds__(256) void k_wswz(const float* __restrict__ W,
                                              unsigned short* __restrict__ Wswz) {
    int t = blockIdx.x * 256 + threadIdx.x;
    if (t < IN_DIM * OUT_DIM) {
        int k = t >> 6, n = t & 63;
        int kt = k >> 5, kin = k & 31;
        int quad = kin >> 3, j = kin & 7;
        int ct = n >> 4, l16 = n & 15;
        int lane = quad * 16 + l16;
        Wswz[(((kt * 4 + ct) * 64 + lane) * 8) + j] = f2bf(W[t]);
    }
}

// ---------------- h = dinv * (x @ W), bf16 MFMA, streaming ----------------
// Two-half K pipeline: stage kt 0..7 as bf16 (32 VGPR), then per kt issue the
// kt+8 load pair, MFMA the current fragment, and convert the arriving data in
// place over the just-consumed A[kt]. Max live ~92 VGPR -> no spill under the
// (512,2) 128-VGPR budget (round-1/2 evidence: arg2 = min BLOCKS/CU; abf[16]
// full-staging demanded ~152 and spilled ~76 MB of scratch traffic at cap 128,
// which also cost the 2nd resident block -> 18.6% occupancy).
__global__ __launch_bounds__(512, 2) void k_gemm(const float* __restrict__ x,
                                              const unsigned short* __restrict__ Wswz,
                                              const int* __restrict__ degi,
                                              unsigned short* __restrict__ h) {
    __shared__ short8 Wlds[64][64];   // 64 KB (full W in bf16 fragment order)
    const int t = threadIdx.x;
    {
        const float4v* s = (const float4v*)Wswz;
        float4v* d = (float4v*)Wlds;
        for (int i = t; i < 4096; i += 512) d[i] = s[i];
    }
    __syncthreads();

    const int lane = t & 63;
    const int quad = lane >> 4, l16 = lane & 15;
    const int wid = blockIdx.x * 8 + (t >> 6);

    // balanced contiguous tile range per wave (6250 over 4096 waves)
    const int t0 = (int)(((long)wid * N_TILES) / GEMM_WAVES);
    const int t1 = (int)(((long)(wid + 1) * N_TILES) / GEMM_WAVES);

    for (int tile = t0; tile < t1; ++tile) {
        const int r0 = tile * 16;
        const float* xrow = x + (size_t)(r0 + l16) * IN_DIM + quad * 8;

        short8 A[8];                       // 32 VGPR, reused in place
#pragma unroll
        for (int kt = 0; kt < 8; ++kt) {
            float4v lo = *(const float4v*)(xrow + kt * 32);
            float4v hi = *(const float4v*)(xrow + kt * 32 + 4);
            A[kt] = cvt8(lo, hi);
        }
        float4v acc[4] = {{0.f,0.f,0.f,0.f},{0.f,0.f,0.f,0.f},
                          {0.f,0.f,0.f,0.f},{0.f,0.f,0.f,0.f}};
#pragma unroll
        for (int kt = 0; kt < 8; ++kt) {
            // issue next-half load pair (latency hidden under this kt's MFMAs)
            float4v lo = *(const float4v*)(xrow + (kt + 8) * 32);
            float4v hi = *(const float4v*)(xrow + (kt + 8) * 32 + 4);
#pragma unroll
            for (int ct = 0; ct < 4; ++ct) {
                short8 bf = Wlds[kt * 4 + ct][lane];
                acc[ct] = __builtin_amdgcn_mfma_f32_16x16x32_bf16(A[kt], bf, acc[ct], 0, 0, 0);
            }
            A[kt] = cvt8(lo, hi);          // overwrite consumed fragment
        }
#pragma unroll
        for (int kt = 0; kt < 8; ++kt) {
#pragma unroll
            for (int ct = 0; ct < 4; ++ct) {
                short8 bf = Wlds[(kt + 8) * 4 + ct][lane];
                acc[ct] = __builtin_amdgcn_mfma_f32_16x16x32_bf16(A[kt], bf, acc[ct], 0, 0, 0);
            }
        }
#pragma unroll
        for (int reg = 0; reg < 4; ++reg) {
            int orow = r0 + quad * 4 + reg;
            float dinv = rsqrtf((float)(degi[orow] + 1));
#pragma unroll
            for (int ct = 0; ct < 4; ++ct)
                h[(size_t)orow * OUT_DIM + ct * 16 + l16] = f2bf(acc[ct][reg] * dinv);
        }
    }
}

// ---------------- gather + bias + log_softmax, one wave per node ----------------
__global__ __launch_bounds__(256) void k_gather(const int* __restrict__ degi,
                                                const int* __restrict__ row_ptr,
                                                const int* __restrict__ csr,
                                                const unsigned short* __restrict__ h,
                                                const float* __restrict__ b,
                                                float* __restrict__ out) {
    int node = blockIdx.x * 4 + (threadIdx.x >> 6);
    int lane = threadIdx.x & 63;
    if (node >= N_NODES) return;
    int cnt  = __builtin_amdgcn_readfirstlane(degi[node]);
    int base = __builtin_amdgcn_readfirstlane(row_ptr[node]);

    float acc = bf2f(h[(size_t)node * OUT_DIM + lane]);
    int e = 0;
    for (; e + 8 <= cnt; e += 8) {
        int s0 = csr[base + e + 0], s1 = csr[base + e + 1];
        int s2 = csr[base + e + 2], s3 = csr[base + e + 3];
        int s4 = csr[base + e + 4], s5 = csr[base + e + 5];
        int s6 = csr[base + e + 6], s7 = csr[base + e + 7];
        float v0 = bf2f(h[(size_t)s0 * OUT_DIM + lane]);
        float v1 = bf2f(h[(size_t)s1 * OUT_DIM + lane]);
        float v2 = bf2f(h[(size_t)s2 * OUT_DIM + lane]);
        float v3 = bf2f(h[(size_t)s3 * OUT_DIM + lane]);
        float v4 = bf2f(h[(size_t)s4 * OUT_DIM + lane]);
        float v5 = bf2f(h[(size_t)s5 * OUT_DIM + lane]);
        float v6 = bf2f(h[(size_t)s6 * OUT_DIM + lane]);
        float v7 = bf2f(h[(size_t)s7 * OUT_DIM + lane]);
        acc += ((v0 + v1) + (v2 + v3)) + ((v4 + v5) + (v6 + v7));
    }
    for (; e < cnt; ++e)
        acc += bf2f(h[(size_t)csr[base + e] * OUT_DIM + lane]);

    float v = acc * rsqrtf((float)(cnt + 1)) + b[lane];
    float m = v;
#pragma unroll
    for (int off = 32; off > 0; off >>= 1) m = fmaxf(m, __shfl_xor(m, off, 64));
    float ex = expf(v - m);
    float s = ex;
#pragma unroll
    for (int off = 32; off > 0; off >>= 1) s += __shfl_xor(s, off, 64);
    out[(size_t)node * OUT_DIM + lane] = v - m - logf(s);
}

extern "C" void kernel_launch(void* const* d_in, const int* in_sizes, int n_in,
                              void* d_out, int out_size, void* d_ws, size_t ws_size,
                              hipStream_t stream) {
    const float* x  = (const float*)d_in[0];
    const int*   ei = (const int*)d_in[1];   // [2, E]: row 0 = src, row 1 = dst
    const float* W  = (const float*)d_in[2];
    const float* b  = (const float*)d_in[3];
    float* out = (float*)d_out;

    char* ws = (char*)d_ws;
    int*            degi       = (int*)(ws + 0);              // 400,000 B
    int*            row_ptr    = (int*)(ws + 400000);         // 400,000 B
    int*            blockHist  = (int*)(ws + 800000);         // 524,288 B
    int*            blockStart = (int*)(ws + 1324288);        // 524,288 B
    int*            bucketBase = (int*)(ws + 1848576);        // 4,100 B (pad to 4,352)
    unsigned short* Wswz       = (unsigned short*)(ws + 1852928);   // 65,536 B
    unsigned short* h          = (unsigned short*)(ws + 1918464);   // 12,800,000 B
    int*            parts      = (int*)(ws + 14718464);       // 6,400,000 B
    int*            csr        = (int*)(ws + 21118464);       // 6,400,000 B  (~27.5 MB total)

    const int* src = ei;
    const int* dst = ei + N_EDGES;

    k_hist1    <<<NPB, 256, 0, stream>>>(dst, blockHist);
    k_offsets  <<<1,   256, 0, stream>>>(blockHist, blockStart, bucketBase);
    k_partition<<<NPB, 256, 0, stream>>>(dst, src, blockStart, parts);
    k_bucket   <<<N_BUCKETS_USED, 256, 0, stream>>>(parts, bucketBase, degi, row_ptr, csr);
    k_wswz     <<<(IN_DIM * OUT_DIM + 255) / 256, 256, 0, stream>>>(W, Wswz);
    k_gemm     <<<512, 512, 0, stream>>>(x, Wswz, degi, h);
    k_gather   <<<(N_NODES + 3) / 4, 256, 0, stream>>>(degi, row_ptr, csr, h, b, out);
}

// Round 4
// 453.818 us; speedup vs baseline: 1.0808x; 1.0808x over previous
//
#include <hip/hip_runtime.h>
#include <math.h>

#define N_NODES 100000
#define N_EDGES 1600000
#define IN_DIM 512
#define OUT_DIM 64
#define NB 1024                    // sort buckets (dst>>7)
#define NPB 128                    // partition blocks
#define CHUNK (N_EDGES / NPB)      // 12500 edges per partition block (exact)
#define N_BUCKETS_USED 782         // ceil(100000/128)
#define N_TILES (N_NODES / 16)     // 6250 exact
#define GEMM_WAVES 4096            // 512 blocks x 8 waves

typedef __attribute__((ext_vector_type(8))) short short8;
typedef __attribute__((ext_vector_type(4))) float float4v;

__device__ __forceinline__ unsigned short f2bf(float f) {   // RNE fp32->bf16
    unsigned int u = __float_as_uint(f);
    u += 0x7fffu + ((u >> 16) & 1u);
    return (unsigned short)(u >> 16);
}
__device__ __forceinline__ float bf2f(unsigned short s) {
    return __uint_as_float(((unsigned int)s) << 16);
}
__device__ __forceinline__ short8 cvt8(float4v lo, float4v hi) {
    union { short8 s8; unsigned short us[8]; } af;
    af.us[0] = f2bf(lo.x); af.us[1] = f2bf(lo.y);
    af.us[2] = f2bf(lo.z); af.us[3] = f2bf(lo.w);
    af.us[4] = f2bf(hi.x); af.us[5] = f2bf(hi.y);
    af.us[6] = f2bf(hi.z); af.us[7] = f2bf(hi.w);
    return af.s8;
}

// ---------------- pass 1: per-block bucket histogram ----------------
__global__ __launch_bounds__(256) void k_hist1(const int* __restrict__ dst,
                                               int* __restrict__ blockHist) {
    __shared__ int hist[NB];
    const int t = threadIdx.x, b = blockIdx.x;
    for (int k = t; k < NB; k += 256) hist[k] = 0;
    __syncthreads();
    const int e0 = b * CHUNK;
    for (int i = t; i < CHUNK; i += 256)
        atomicAdd(&hist[dst[e0 + i] >> 7], 1);
    __syncthreads();
    for (int k = t; k < NB; k += 256) blockHist[b * NB + k] = hist[k];
}

// ---------------- pass 2: bucket bases + per-(block,bucket) starts ----------------
__global__ __launch_bounds__(256) void k_offsets(const int* __restrict__ blockHist,
                                                 int* __restrict__ blockStart,
                                                 int* __restrict__ bucketBase) {
    __shared__ int colsum[NB];
    __shared__ int bbase[NB + 1];
    __shared__ int wtot[4];
    const int t = threadIdx.x, lane = t & 63, w = t >> 6;
    for (int k = t; k < NB; k += 256) {
        int s = 0;
        for (int b = 0; b < NPB; ++b) s += blockHist[b * NB + k];
        colsum[k] = s;
    }
    __syncthreads();
    int c0 = colsum[t * 4 + 0], c1 = colsum[t * 4 + 1];
    int c2 = colsum[t * 4 + 2], c3 = colsum[t * 4 + 3];
    int tsum = c0 + c1 + c2 + c3;
    int incl = tsum;
#pragma unroll
    for (int off = 1; off < 64; off <<= 1) {
        int u = __shfl_up(incl, off, 64);
        if (lane >= off) incl += u;
    }
    if (lane == 63) wtot[w] = incl;
    __syncthreads();
    int woff = 0;
#pragma unroll
    for (int k2 = 0; k2 < 4; ++k2) if (k2 < w) woff += wtot[k2];
    int excl = woff + incl - tsum;
    bbase[t * 4 + 0] = excl;
    bbase[t * 4 + 1] = excl + c0;
    bbase[t * 4 + 2] = excl + c0 + c1;
    bbase[t * 4 + 3] = excl + c0 + c1 + c2;
    if (t == 255) bbase[NB] = excl + tsum;   // == N_EDGES
    __syncthreads();
    for (int k = t; k < NB + 1; k += 256) bucketBase[k] = bbase[k];
    for (int k = t; k < NB; k += 256) {
        int run = bbase[k];
        for (int b = 0; b < NPB; ++b) {
            blockStart[b * NB + k] = run;
            run += blockHist[b * NB + k];
        }
    }
}

// ---------------- pass 3: partition edges into buckets (packed codes) ----------------
__global__ __launch_bounds__(256) void k_partition(const int* __restrict__ dst,
                                                   const int* __restrict__ src,
                                                   const int* __restrict__ blockStart,
                                                   int* __restrict__ parts) {
    __shared__ int cursor[NB];
    const int t = threadIdx.x, b = blockIdx.x;
    for (int k = t; k < NB; k += 256) cursor[k] = blockStart[b * NB + k];
    __syncthreads();
    const int e0 = b * CHUNK;
    for (int i = t; i < CHUNK; i += 256) {
        int d = dst[e0 + i];
        int s = src[e0 + i];
        int k = d >> 7;
        int pos = atomicAdd(&cursor[k], 1);          // LDS atomic (fast)
        parts[pos] = ((d & 127) << 17) | s;           // src < 2^17
    }
}

// ---------------- pass 4: per-bucket counting sort -> deg, row_ptr, csr ----------------
__global__ __launch_bounds__(256) void k_bucket(const int* __restrict__ parts,
                                                const int* __restrict__ bucketBase,
                                                int* __restrict__ degi,
                                                int* __restrict__ row_ptr,
                                                int* __restrict__ csr) {
    __shared__ int cnt[128];
    __shared__ int cur[128];
    __shared__ int wtot[2];
    const int t = threadIdx.x, k = blockIdx.x;
    const int base = bucketBase[k];
    const int n    = bucketBase[k + 1] - base;
    if (t < 128) cnt[t] = 0;
    __syncthreads();
    for (int i = t; i < n; i += 256)
        atomicAdd(&cnt[parts[base + i] >> 17], 1);
    __syncthreads();
    int incl = 0, v = 0;
    if (t < 128) {
        int lane = t & 63;
        v = cnt[t];
        incl = v;
#pragma unroll
        for (int off = 1; off < 64; off <<= 1) {
            int u = __shfl_up(incl, off, 64);
            if (lane >= off) incl += u;
        }
        if (lane == 63) wtot[t >> 6] = incl;
    }
    __syncthreads();
    if (t < 128) {
        int excl = incl - v + ((t >> 6) ? wtot[0] : 0);
        cur[t] = excl;
        int node = k * 128 + t;
        if (node < N_NODES) {
            degi[node]    = v;
            row_ptr[node] = base + excl;
        }
    }
    __syncthreads();
    for (int i = t; i < n; i += 256) {
        int code = parts[base + i];
        int nl = code >> 17, s = code & 0x1FFFF;
        int pos = atomicAdd(&cur[nl], 1);            // LDS atomic
        csr[base + pos] = s;                         // contiguous ~8KB region, L2-resident
    }
}

// ---------------- W swizzle: fp32 [512][64] -> bf16 B-fragment order ----------------
__global__ __launch_bounds__(256) void k_wswz(const float* __restrict__ W,
                                              unsigned short* __restrict__ Wswz) {
    int t = blockIdx.x * 256 + threadIdx.x;
    if (t < IN_DIM * OUT_DIM) {
        int k = t >> 6, n = t & 63;
        int kt = k >> 5, kin = k & 31;
        int quad = kin >> 3, j = kin & 7;
        int ct = n >> 4, l16 = n & 15;
        int lane = quad * 16 + l16;
        Wswz[(((kt * 4 + ct) * 64 + lane) * 8) + j] = f2bf(W[t]);
    }
}

// ---------------- h = dinv * (x @ W), bf16 MFMA, streaming ----------------
// Quarter-K register pipeline inside a #pragma unroll 1 loop: only ONE quarter
// (4 load-pairs = 32 VGPR) is ever in flight, and the non-unrolled loop boundary
// structurally caps scheduler load-hoisting (R2/R3 evidence: fully-unrolled K
// let the scheduler hoist ~10 load-pairs -> ~150 VGPR demand -> 43 MB spill at
// the 128 cap, and scratch cost the 2nd resident block -> 17% occupancy).
// Target: true demand ~105 VGPR, zero scratch, 16 waves/CU.
__global__ __launch_bounds__(512, 2) void k_gemm(const float* __restrict__ x,
                                              const unsigned short* __restrict__ Wswz,
                                              const int* __restrict__ degi,
                                              unsigned short* __restrict__ h) {
    __shared__ short8 Wlds[64][64];   // 64 KB (full W in bf16 fragment order)
    const int t = threadIdx.x;
    {
        const float4v* s = (const float4v*)Wswz;
        float4v* d = (float4v*)Wlds;
        for (int i = t; i < 4096; i += 512) d[i] = s[i];
    }
    __syncthreads();

    const int lane = t & 63;
    const int quad = lane >> 4, l16 = lane & 15;
    const int wid = blockIdx.x * 8 + (t >> 6);

    // balanced contiguous tile range per wave (6250 over 4096 waves)
    const int t0 = (int)(((long)wid * N_TILES) / GEMM_WAVES);
    const int t1 = (int)(((long)(wid + 1) * N_TILES) / GEMM_WAVES);

    for (int tile = t0; tile < t1; ++tile) {
        const int r0 = tile * 16;
        const float* xrow = x + (size_t)(r0 + l16) * IN_DIM + quad * 8;

        float4v plo[4], phi[4];            // the ONLY in-flight buffer (32 VGPR)
#pragma unroll
        for (int kt = 0; kt < 4; ++kt) {
            plo[kt] = *(const float4v*)(xrow + kt * 32);
            phi[kt] = *(const float4v*)(xrow + kt * 32 + 4);
        }
        float4v acc[4] = {{0.f,0.f,0.f,0.f},{0.f,0.f,0.f,0.f},
                          {0.f,0.f,0.f,0.f},{0.f,0.f,0.f,0.f}};

#pragma unroll 1
        for (int kq = 0; kq < 4; ++kq) {
            short8 A[4];
#pragma unroll
            for (int kt = 0; kt < 4; ++kt) A[kt] = cvt8(plo[kt], phi[kt]);
            if (kq < 3) {                   // prefetch next quarter (uniform branch)
#pragma unroll
                for (int kt = 0; kt < 4; ++kt) {
                    plo[kt] = *(const float4v*)(xrow + (kq + 1) * 128 + kt * 32);
                    phi[kt] = *(const float4v*)(xrow + (kq + 1) * 128 + kt * 32 + 4);
                }
            }
#pragma unroll
            for (int kt = 0; kt < 4; ++kt) {
#pragma unroll
                for (int ct = 0; ct < 4; ++ct) {
                    short8 bf = Wlds[(kq * 4 + kt) * 4 + ct][lane];
                    acc[ct] = __builtin_amdgcn_mfma_f32_16x16x32_bf16(A[kt], bf, acc[ct], 0, 0, 0);
                }
            }
        }

#pragma unroll
        for (int reg = 0; reg < 4; ++reg) {
            int orow = r0 + quad * 4 + reg;
            float dinv = rsqrtf((float)(degi[orow] + 1));
#pragma unroll
            for (int ct = 0; ct < 4; ++ct)
                h[(size_t)orow * OUT_DIM + ct * 16 + l16] = f2bf(acc[ct][reg] * dinv);
        }
    }
}

// ---------------- gather + bias + log_softmax, one wave per node ----------------
__global__ __launch_bounds__(256) void k_gather(const int* __restrict__ degi,
                                                const int* __restrict__ row_ptr,
                                                const int* __restrict__ csr,
                                                const unsigned short* __restrict__ h,
                                                const float* __restrict__ b,
                                                float* __restrict__ out) {
    int node = blockIdx.x * 4 + (threadIdx.x >> 6);
    int lane = threadIdx.x & 63;
    if (node >= N_NODES) return;
    int cnt  = __builtin_amdgcn_readfirstlane(degi[node]);
    int base = __builtin_amdgcn_readfirstlane(row_ptr[node]);

    float acc = bf2f(h[(size_t)node * OUT_DIM + lane]);
    int e = 0;
    for (; e + 8 <= cnt; e += 8) {
        int s0 = csr[base + e + 0], s1 = csr[base + e + 1];
        int s2 = csr[base + e + 2], s3 = csr[base + e + 3];
        int s4 = csr[base + e + 4], s5 = csr[base + e + 5];
        int s6 = csr[base + e + 6], s7 = csr[base + e + 7];
        float v0 = bf2f(h[(size_t)s0 * OUT_DIM + lane]);
        float v1 = bf2f(h[(size_t)s1 * OUT_DIM + lane]);
        float v2 = bf2f(h[(size_t)s2 * OUT_DIM + lane]);
        float v3 = bf2f(h[(size_t)s3 * OUT_DIM + lane]);
        float v4 = bf2f(h[(size_t)s4 * OUT_DIM + lane]);
        float v5 = bf2f(h[(size_t)s5 * OUT_DIM + lane]);
        float v6 = bf2f(h[(size_t)s6 * OUT_DIM + lane]);
        float v7 = bf2f(h[(size_t)s7 * OUT_DIM + lane]);
        acc += ((v0 + v1) + (v2 + v3)) + ((v4 + v5) + (v6 + v7));
    }
    for (; e < cnt; ++e)
        acc += bf2f(h[(size_t)csr[base + e] * OUT_DIM + lane]);

    float v = acc * rsqrtf((float)(cnt + 1)) + b[lane];
    float m = v;
#pragma unroll
    for (int off = 32; off > 0; off >>= 1) m = fmaxf(m, __shfl_xor(m, off, 64));
    float ex = expf(v - m);
    float s = ex;
#pragma unroll
    for (int off = 32; off > 0; off >>= 1) s += __shfl_xor(s, off, 64);
    out[(size_t)node * OUT_DIM + lane] = v - m - logf(s);
}

extern "C" void kernel_launch(void* const* d_in, const int* in_sizes, int n_in,
                              void* d_out, int out_size, void* d_ws, size_t ws_size,
                              hipStream_t stream) {
    const float* x  = (const float*)d_in[0];
    const int*   ei = (const int*)d_in[1];   // [2, E]: row 0 = src, row 1 = dst
    const float* W  = (const float*)d_in[2];
    const float* b  = (const float*)d_in[3];
    float* out = (float*)d_out;

    char* ws = (char*)d_ws;
    int*            degi       = (int*)(ws + 0);              // 400,000 B
    int*            row_ptr    = (int*)(ws + 400000);         // 400,000 B
    int*            blockHist  = (int*)(ws + 800000);         // 524,288 B
    int*            blockStart = (int*)(ws + 1324288);        // 524,288 B
    int*            bucketBase = (int*)(ws + 1848576);        // 4,100 B (pad to 4,352)
    unsigned short* Wswz       = (unsigned short*)(ws + 1852928);   // 65,536 B
    unsigned short* h          = (unsigned short*)(ws + 1918464);   // 12,800,000 B
    int*            parts      = (int*)(ws + 14718464);       // 6,400,000 B
    int*            csr        = (int*)(ws + 21118464);       // 6,400,000 B  (~27.5 MB total)

    const int* src = ei;
    const int* dst = ei + N_EDGES;

    k_hist1    <<<NPB, 256, 0, stream>>>(dst, blockHist);
    k_offsets  <<<1,   256, 0, stream>>>(blockHist, blockStart, bucketBase);
    k_partition<<<NPB, 256, 0, stream>>>(dst, src, blockStart, parts);
    k_bucket   <<<N_BUCKETS_USED, 256, 0, stream>>>(parts, bucketBase, degi, row_ptr, csr);
    k_wswz     <<<(IN_DIM * OUT_DIM + 255) / 256, 256, 0, stream>>>(W, Wswz);
    k_gemm     <<<512, 512, 0, stream>>>(x, Wswz, degi, h);
    k_gather   <<<(N_NODES + 3) / 4, 256, 0, stream>>>(degi, row_ptr, csr, h, b, out);
}